// Round 11
// baseline (815.357 us; speedup 1.0000x reference)
//
#include <hip/hip_runtime.h>
#include <hip/hip_bf16.h>

// Problem constants
#define NBANDS 5
#define BATCH  512
#define KQN    64     // queries per sample
#define DM     200    // model dim
#define NHEAD  4
#define HD     50     // head dim
#define HIDW   512    // router hidden
#define TKV    320    // NBANDS*KQN keys
#define FIN    64000  // NBANDS*KQN*DM
#define BSTRIDE 6553600  // BATCH*KQN*DM floats per band
#define KSPLIT 50
#define KCH    1280   // FIN/KSPLIT ; 12800/1280=10 -> z-slice within one band
#define NCH    40     // KCH/32 chunks (BK=32) per block
#define NTT    13     // N-tiles of 16 covering 200 (13*16=208)
#define KST    7      // K-steps of 32 covering 200 (7*32=224)
#define NTKV   25     // N-tiles of 16 covering 400

typedef __bf16  bf16x8 __attribute__((ext_vector_type(8)));
typedef float   f32x4  __attribute__((ext_vector_type(4)));

static __device__ inline unsigned short f2bf(float f) {
    __hip_bfloat16 h = __float2bfloat16(f);
    return *reinterpret_cast<unsigned short*>(&h);
}
static __device__ inline float bf2f(unsigned short u) {
    union { unsigned int i; float f; } x;
    x.i = ((unsigned int)u) << 16;
    return x.f;
}
static __device__ inline bf16x8 bf8zero() {
    union { bf16x8 v; unsigned int u[4]; } z;
    z.u[0] = z.u[1] = z.u[2] = z.u[3] = 0u;
    return z.v;
}
// Markidis split of 8 consecutive fp32 into hi/lo bf16x8
static __device__ inline void split8(const float4& a, const float4& b,
                                     bf16x8& hi, bf16x8& lo) {
    union { bf16x8 v; unsigned short u[8]; } H, L;
    const float xs[8] = {a.x, a.y, a.z, a.w, b.x, b.y, b.z, b.w};
#pragma unroll
    for (int i = 0; i < 8; ++i) {
        H.u[i] = f2bf(xs[i]);
        L.u[i] = f2bf(xs[i] - bf2f(H.u[i]));
    }
    hi = H.v; lo = L.v;
}
// plain bf16 round of 8 consecutive fp32
static __device__ inline bf16x8 round8(const float4& a, const float4& b) {
    union { bf16x8 v; unsigned short u[8]; } H;
    const float xs[8] = {a.x, a.y, a.z, a.w, b.x, b.y, b.z, b.w};
#pragma unroll
    for (int i = 0; i < 8; ++i) H.u[i] = f2bf(xs[i]);
    return H.v;
}

// ---------------------------------------------------------------------------
// K0: split w1 into FRAGMENT-MAJOR Markidis hi/lo bf16 planes, once.
// Tile = (oj in [0,4) of 128 rows, kc in [0,1000) of 64 k):
// slot = (ks*8+nt)*64 + lane holds
// w1[oj*128 + nt*16 + (lane&15)][kc*64 + ks*32 + (lane>>4)*8 + e], e=0..7.
// Each ks-half (8 KB/plane, nt 0..7) is CONTIGUOUS -> BK=32 slabs DMA linearly.
// ---------------------------------------------------------------------------
__global__ __launch_bounds__(256) void k_splitw1(
    const float* __restrict__ w1, unsigned short* __restrict__ BHp,
    unsigned short* __restrict__ BLp)
{
    __shared__ __align__(16) unsigned short Hs[128][72];
    __shared__ __align__(16) unsigned short Ls[128][72];
    const int kc = blockIdx.x;        // 0..999
    const int jt = blockIdx.y;        // 0..3
    const int t  = threadIdx.x;
    const int rl0 = t >> 4, cl4 = (t & 15) * 4;
#pragma unroll
    for (int i = 0; i < 8; ++i) {
        const int row = rl0 + i * 16;
        const float4 v = *(const float4*)(w1
            + (size_t)(jt * 128 + row) * FIN + kc * 64 + cl4);
        ushort4 hh, ll;
        hh.x = f2bf(v.x); ll.x = f2bf(v.x - bf2f(hh.x));
        hh.y = f2bf(v.y); ll.y = f2bf(v.y - bf2f(hh.y));
        hh.z = f2bf(v.z); ll.z = f2bf(v.z - bf2f(hh.z));
        hh.w = f2bf(v.w); ll.w = f2bf(v.w - bf2f(hh.w));
        *(ushort4*)&Hs[row][cl4] = hh;
        *(ushort4*)&Ls[row][cl4] = ll;
    }
    __syncthreads();
    const size_t tbase = ((size_t)(jt * 1000 + kc)) << 13;   // ushort units
#pragma unroll
    for (int i = 0; i < 4; ++i) {
        const int slot = i * 256 + t;          // 0..1023
        const int ksnt = slot >> 6, lane = slot & 63;
        const int ks = ksnt >> 3, nt = ksnt & 7;
        const int row = nt * 16 + (lane & 15);
        const int col = ks * 32 + (lane >> 4) * 8;
        *(uint4*)(BHp + tbase + (size_t)slot * 8) = *(const uint4*)&Hs[row][col];
        *(uint4*)(BLp + tbase + (size_t)slot * 8) = *(const uint4*)&Ls[row][col];
    }
}

// ---------------------------------------------------------------------------
// K1 (v6): router GEMM — single barrier per chunk.
// R10 budget: per chunk/CU MFMA ~3100 cyc, LDS-read ~2300, measured 9600 ->
// ~4000 cyc structural overhead = two-barrier A-reuse chain (compute ->
// barrier -> writeA -> barrier), each barrier also vmcnt(0)-draining the
// B-DMA. Fix: double-buffer A in LDS too (128 KB total, still 1 blk/CU):
// per chunk {stageB(c+1); loadA(c+1); compute(c); writeA(c+1); barrier}.
// Buffer (c+1)&1's last reader was compute(c-1), finished before previous
// barrier -> race-free with ONE barrier/chunk. Product order per acc
// unchanged (AhBh,AlBh,AhBl; ascending k) -> bit-identical logits.
// ---------------------------------------------------------------------------
__global__ __launch_bounds__(512, 2) void k_router_mfma(
    const float* __restrict__ bands, const unsigned short* __restrict__ BHp,
    const unsigned short* __restrict__ BLp, float* __restrict__ part)
{
    __shared__ __align__(16) unsigned short BsH[2][8192];   // 2 x 16 KB
    __shared__ __align__(16) unsigned short BsL[2][8192];   // 2 x 16 KB
    __shared__ __align__(16) unsigned short Ah[2][8192];    // 2 x 16 KB
    __shared__ __align__(16) unsigned short Al[2][8192];    // 2 x 16 KB

    // grid: x=jt(2), y=bt(2), z=50 ; 200 blocks = 8 XCD x 25 (bijective)
    const int lin = (blockIdx.z << 2) | (blockIdx.y << 1) | blockIdx.x;
    const int logical = (lin & 7) * 25 + (lin >> 3);
    const int z   = logical >> 2;          // 0..49
    const int rem = logical & 3;
    const int bt  = rem >> 1, jt = rem & 1;

    const int t = threadIdx.x;
    const int w = t >> 6, lane = t & 63;   // w in [0,8)
    const int lm = lane & 15, quad = lane >> 4;
    const int wr = w >> 2, wc = w & 3;     // 2x4 wave grid

    // A: this wave stages rows bt*256 + w*32 + rt*16 + lm (rt=0,1)
    const float* abase = bands + (size_t)(z / 10) * BSTRIDE
                       + (size_t)(bt * 256 + w * 32 + lm) * 12800
                       + (z % 10) * KCH + quad * 8;

    // async stage of one BK=32 B slab (16 KB hi + 16 KB lo) into buffer buf
    auto stageB = [&](int c, int buf) {
        const int kc = z * 20 + (c >> 1);
        const int ks = c & 1;
#pragma unroll
        for (int p = 0; p < 4; ++p) {
            const int plane = p >> 1, r = p & 1;   // r: oj half (128 rows)
            const unsigned short* src = (plane ? BLp : BHp)
                + ((size_t)((jt * 2 + r) * 1000 + kc) << 13) + (ks << 12)
                + (size_t)t * 8;
            unsigned short* dst = (plane ? &BsL[buf][0] : &BsH[buf][0])
                + (r << 12) + ((t >> 6) << 9);     // + lane*16B by HW
            __builtin_amdgcn_global_load_lds(
                (const __attribute__((address_space(1))) unsigned int*)src,
                (__attribute__((address_space(3))) unsigned int*)dst, 16, 0, 0);
        }
    };

    float4 ar[4];     // A prefetch regs: 2 row-tiles x 8 floats
    auto loadA = [&](int c) {
        const float* ap = abase + c * 32;
        ar[0] = *(const float4*)(ap);
        ar[1] = *(const float4*)(ap + 4);
        ar[2] = *(const float4*)(ap + (size_t)16 * 12800);
        ar[3] = *(const float4*)(ap + (size_t)16 * 12800 + 4);
    };
    auto writeA = [&](int buf) {
        bf16x8 h0, l0, h1, l1;
        split8(ar[0], ar[1], h0, l0);
        split8(ar[2], ar[3], h1, l1);
        *(bf16x8*)&Ah[buf][(w * 2 + 0) * 512 + lane * 8] = h0;
        *(bf16x8*)&Al[buf][(w * 2 + 0) * 512 + lane * 8] = l0;
        *(bf16x8*)&Ah[buf][(w * 2 + 1) * 512 + lane * 8] = h1;
        *(bf16x8*)&Al[buf][(w * 2 + 1) * 512 + lane * 8] = l1;
    };

    f32x4 acc[8][4];
#pragma unroll
    for (int rs = 0; rs < 8; ++rs)
#pragma unroll
        for (int nt = 0; nt < 4; ++nt) acc[rs][nt] = (f32x4){0.f, 0.f, 0.f, 0.f};

    // prologue: A(0)+B(0) into buffer 0
    loadA(0);
    stageB(0, 0);
    __syncthreads();                 // B(0) DMA drained; ar = A(0)
    writeA(0);
    __syncthreads();                 // A(0) visible

    for (int c = 0; c < NCH; ++c) {
        const int buf = c & 1;
        if (c + 1 < NCH) {           // fly next A/B under compute(c)
            stageB(c + 1, buf ^ 1);
            loadA(c + 1);
        }
        // ---- compute chunk c: 96 MFMAs/wave ----
        const unsigned short* bh = &BsH[buf][(wc * 4) * 512 + lane * 8];
        const unsigned short* bl = &BsL[buf][(wc * 4) * 512 + lane * 8];
        const unsigned short* ahp = &Ah[buf][(wr * 8) * 512 + lane * 8];
        const unsigned short* alp = &Al[buf][(wr * 8) * 512 + lane * 8];
        bf16x8 bhv[4], blv[4];
#pragma unroll
        for (int nt = 0; nt < 4; ++nt) {
            bhv[nt] = *(const bf16x8*)(bh + nt * 512);
            blv[nt] = *(const bf16x8*)(bl + nt * 512);
        }
#pragma unroll
        for (int rs = 0; rs < 8; ++rs) {
            const bf16x8 a_h = *(const bf16x8*)(ahp + rs * 512);
            const bf16x8 a_l = *(const bf16x8*)(alp + rs * 512);
#pragma unroll
            for (int nt = 0; nt < 4; ++nt) {
                acc[rs][nt] = __builtin_amdgcn_mfma_f32_16x16x32_bf16(a_h, bhv[nt], acc[rs][nt], 0, 0, 0);
                acc[rs][nt] = __builtin_amdgcn_mfma_f32_16x16x32_bf16(a_l, bhv[nt], acc[rs][nt], 0, 0, 0);
                acc[rs][nt] = __builtin_amdgcn_mfma_f32_16x16x32_bf16(a_h, blv[nt], acc[rs][nt], 0, 0, 0);
            }
        }
        if (c + 1 < NCH) writeA(buf ^ 1);   // A(c+1) -> other buffer (no reader)
        __syncthreads();             // drains DMA(c+1) + publishes A(c+1)
    }

    float* po = part + (size_t)z * (BATCH * HIDW);
    const int j0 = jt * 256 + wc * 64;
    const int b0 = bt * 256 + wr * 128;
#pragma unroll
    for (int rs = 0; rs < 8; ++rs) {
#pragma unroll
        for (int nt = 0; nt < 4; ++nt) {
            const int jj = j0 + nt * 16 + lm;
#pragma unroll
            for (int reg = 0; reg < 4; ++reg) {
                const int bb = b0 + rs * 16 + quad * 4 + reg;
                po[(size_t)bb * HIDW + jj] = acc[rs][nt][reg];
            }
        }
    }
}

// ---------------------------------------------------------------------------
// K2: h = relu(sum_z part + b1)
// ---------------------------------------------------------------------------
__global__ __launch_bounds__(256) void k_reduce_relu(
    const float* __restrict__ part, const float* __restrict__ b1,
    float* __restrict__ h)
{
    const int tid = blockIdx.x * 256 + threadIdx.x;  // < BATCH*HIDW
    float s = b1[tid & (HIDW - 1)];
#pragma unroll 10
    for (int z = 0; z < KSPLIT; ++z) s += part[z * (BATCH * HIDW) + tid];
    h[tid] = fmaxf(s, 0.f);
}

// ---------------------------------------------------------------------------
// K2c: pack wq (ipw rows 0..199) and out_w into FRAGMENT-MAJOR Markidis
// hi/lo bf16 planes.
// ---------------------------------------------------------------------------
__global__ __launch_bounds__(256) void k_wpack(
    const float* __restrict__ ipw, const float* __restrict__ outw,
    unsigned short* __restrict__ WqHp, unsigned short* __restrict__ WqLp,
    unsigned short* __restrict__ OwHp, unsigned short* __restrict__ OwLp)
{
    const int p = blockIdx.x;          // 0..90 : ks*13+nt
    const int ks = p / NTT, nt = p - ks * NTT;
    const int t = threadIdx.x;
    const int lane = t >> 2, e0 = (t & 3) * 2;
    const int lm = lane & 15, quad = lane >> 4;
    const int row = nt * 16 + lm;
    const int k  = ks * 32 + quad * 8 + e0;
    const float* src = (blockIdx.y == 0) ? ipw : outw;   // wq = ipw rows 0..199
    unsigned short* dh = (blockIdx.y == 0) ? WqHp : OwHp;
    unsigned short* dl = (blockIdx.y == 0) ? WqLp : OwLp;
    float v0 = 0.f, v1 = 0.f;
    if (row < DM && k < DM) {          // k even, so k<200 => k+1<=199 valid
        v0 = src[(size_t)row * DM + k];
        v1 = src[(size_t)row * DM + k + 1];
    }
    const int off = (p << 9) + (lane << 3) + e0;
    const unsigned short h0 = f2bf(v0), h1 = f2bf(v1);
    dh[off]     = h0;
    dh[off + 1] = h1;
    dl[off]     = f2bf(v0 - bf2f(h0));
    dl[off + 1] = f2bf(v1 - bf2f(h1));
}

// ---------------------------------------------------------------------------
// K2d: pack wk|wv (ipw rows 200..599) into ONE fragment-major bf16 plane.
// ---------------------------------------------------------------------------
__global__ __launch_bounds__(256) void k_wpack_kv(
    const float* __restrict__ ipw, unsigned short* __restrict__ Wkv)
{
    const int p = blockIdx.x;          // 0..174 : ks*25+nt
    const int ks = p / NTKV, nt = p - ks * NTKV;
    const int t = threadIdx.x;
    const int lane = t >> 2, e0 = (t & 3) * 2;
    const int lm = lane & 15, quad = lane >> 4;
    const int row = nt * 16 + lm;                 // 0..399, always valid
    const int k  = ks * 32 + quad * 8 + e0;
    float v0 = 0.f, v1 = 0.f;
    if (k < DM) {
        v0 = ipw[(size_t)(DM + row) * DM + k];
        v1 = ipw[(size_t)(DM + row) * DM + k + 1];
    }
    const int off = (p << 9) + (lane << 3) + e0;
    Wkv[off]     = f2bf(v0);
    Wkv[off + 1] = f2bf(v1);
}

// ---------------------------------------------------------------------------
// K3: logits = h @ w2^T + b2 ; sel = argmax
// ---------------------------------------------------------------------------
__global__ __launch_bounds__(256) void k_argmax(
    const float* __restrict__ h, const float* __restrict__ w2,
    const float* __restrict__ b2, int* __restrict__ sel)
{
    __shared__ float red[NBANDS][256];
    const int b = blockIdx.x, t = threadIdx.x;
    float acc[NBANDS] = {0.f, 0.f, 0.f, 0.f, 0.f};
    for (int j = t; j < HIDW; j += 256) {
        const float hv = h[b * HIDW + j];
#pragma unroll
        for (int n = 0; n < NBANDS; ++n)
            acc[n] = fmaf(hv, w2[n * HIDW + j], acc[n]);
    }
#pragma unroll
    for (int n = 0; n < NBANDS; ++n) red[n][t] = acc[n];
    __syncthreads();
    for (int s = 128; s > 0; s >>= 1) {
        if (t < s) {
#pragma unroll
            for (int n = 0; n < NBANDS; ++n) red[n][t] += red[n][t + s];
        }
        __syncthreads();
    }
    if (t == 0) {
        int best = 0;
        float bv = red[0][0] + b2[0];
        for (int n = 1; n < NBANDS; ++n) {
            const float v = red[n][0] + b2[n];
            if (v > bv) { bv = v; best = n; }
        }
        sel[b] = best;
    }
}

// ---------------------------------------------------------------------------
// Shared MFMA core for the two [64x200]@[200x200]^T projections.
// ---------------------------------------------------------------------------
template<bool BF16OUT>
static __device__ inline void proj_core(
    const float* __restrict__ x0,            // 64 rows x 200 fp32, stride DM
    const unsigned short* __restrict__ Ph,   // packed hi plane
    const unsigned short* __restrict__ Pl,   // packed lo plane
    const float* __restrict__ bias,          // 200
    void* __restrict__ outp)                 // 64 rows x 200 (bf16 or f32)
{
    const int t = threadIdx.x;
    const int w = t >> 6, lane = t & 63;
    const int lm = lane & 15, quad = lane >> 4;
    const int m0 = w * 16;
    const float* xrow = x0 + (size_t)(m0 + lm) * DM;

    f32x4 acc[NTT];
#pragma unroll
    for (int nt = 0; nt < NTT; ++nt) acc[nt] = (f32x4){0.f, 0.f, 0.f, 0.f};

#pragma unroll
    for (int ks = 0; ks < KST; ++ks) {
        const int k0 = ks * 32 + quad * 8;
        bf16x8 a_h = bf8zero(), a_l = bf8zero();
        if (k0 + 8 <= DM) {      // ks=6: only quad 0 (k=192..199) has data
            const float4 xa = *(const float4*)(xrow + k0);
            const float4 xb = *(const float4*)(xrow + k0 + 4);
            split8(xa, xb, a_h, a_l);
        }
        const unsigned short* ph = Ph + ((ks * NTT) << 9) + (lane << 3);
        const unsigned short* pl = Pl + ((ks * NTT) << 9) + (lane << 3);
#pragma unroll
        for (int nt = 0; nt < NTT; ++nt) {
            const bf16x8 b_h = *(const bf16x8*)(ph + (nt << 9));
            const bf16x8 b_l = *(const bf16x8*)(pl + (nt << 9));
            acc[nt] = __builtin_amdgcn_mfma_f32_16x16x32_bf16(a_h, b_h, acc[nt], 0, 0, 0);
            acc[nt] = __builtin_amdgcn_mfma_f32_16x16x32_bf16(a_l, b_h, acc[nt], 0, 0, 0);
            acc[nt] = __builtin_amdgcn_mfma_f32_16x16x32_bf16(a_h, b_l, acc[nt], 0, 0, 0);
        }
    }
#pragma unroll
    for (int nt = 0; nt < NTT; ++nt) {
        const int col = nt * 16 + lm;
        if (col < DM) {
            const float bs = bias[col];
#pragma unroll
            for (int reg = 0; reg < 4; ++reg) {
                const int row = m0 + quad * 4 + reg;
                const float v = acc[nt][reg] + bs;
                if (BF16OUT)
                    ((unsigned short*)outp)[(size_t)row * DM + col] = f2bf(v);
                else
                    ((float*)outp)[(size_t)row * DM + col] = v;
            }
        }
    }
}

// K4: q projection for the selected band -> bf16
__global__ __launch_bounds__(256) void k_qproj_mfma(
    const float* __restrict__ bands, const int* __restrict__ sel,
    const unsigned short* __restrict__ WqHp, const unsigned short* __restrict__ WqLp,
    const float* __restrict__ ipb, unsigned short* __restrict__ qb)
{
    const int b = blockIdx.x;
    const int band = sel[b];
    const float* x0 = bands + (size_t)((band * BATCH + b) * KQN) * DM;
    proj_core<true>(x0, WqHp, WqLp, ipb, qb + (size_t)(b * KQN) * DM);
}

// K7: out = o @ out_w^T + out_b (fp32 out)
__global__ __launch_bounds__(256) void k_outproj_mfma(
    const float* __restrict__ obuf, const unsigned short* __restrict__ OwHp,
    const unsigned short* __restrict__ OwLp, const float* __restrict__ outb,
    float* __restrict__ out)
{
    const int b = blockIdx.x;
    proj_core<false>(obuf + (size_t)(b * KQN) * DM, OwHp, OwLp, outb,
                     out + (size_t)(b * KQN) * DM);
}

// ---------------------------------------------------------------------------
// K5: kv projection — A in registers, B async double-buffered LDS (R4 win).
// ---------------------------------------------------------------------------
__global__ __launch_bounds__(256) void k_kvproj_lds(
    const float* __restrict__ bands, const unsigned short* __restrict__ Wkv,
    const float* __restrict__ ipb, __hip_bfloat16* __restrict__ Kp,
    __hip_bfloat16* __restrict__ Vp)
{
    __shared__ __align__(16) unsigned short Bs[2][NTKV * 512];  // 2 x 25 KB
    const int t = threadIdx.x;
    const int w = t >> 6, lane = t & 63;
    const int lm = lane & 15, quad = lane >> 4;
    const int m0 = w * 16;
    const int M0 = blockIdx.x * 64;

    // this wave's A row: one batch, one band, kk = row within band
    const int gg = M0 + m0 + lm;
    const int bb = gg / TKV, tk = gg - bb * TKV;
    const int band = tk >> 6, kk = tk & 63;
    const float* xrow = bands + (size_t)((band * BATCH + bb) * KQN + kk) * DM;

    float4 ar[2 * KST];
#pragma unroll
    for (int ks = 0; ks < KST; ++ks) {
        const int k0 = ks * 32 + quad * 8;
        if (k0 + 8 <= DM) {
            ar[2 * ks]     = *(const float4*)(xrow + k0);
            ar[2 * ks + 1] = *(const float4*)(xrow + k0 + 4);
        }
    }
    bf16x8 a[KST];
#pragma unroll
    for (int ks = 0; ks < KST; ++ks) {
        const int k0 = ks * 32 + quad * 8;
        a[ks] = (k0 + 8 <= DM) ? round8(ar[2 * ks], ar[2 * ks + 1]) : bf8zero();
    }

    auto stage = [&](int ks, int buf) {
        const unsigned short* src = Wkv + ((ks * NTKV) << 9);
#pragma unroll
        for (int pass = 0; pass < 6; ++pass) {
            const int i = pass * 256 + t;              // 16B-unit index
            __builtin_amdgcn_global_load_lds(
                (const __attribute__((address_space(1))) unsigned int*)(src + (size_t)i * 8),
                (__attribute__((address_space(3))) unsigned int*)&Bs[buf][(pass * 256 + w * 64) * 8],
                16, 0, 0);
        }
        if (t < 64) {                                   // tail: wave 0 only
            __builtin_amdgcn_global_load_lds(
                (const __attribute__((address_space(1))) unsigned int*)(src + (size_t)(1536 + lane) * 8),
                (__attribute__((address_space(3))) unsigned int*)&Bs[buf][1536 * 8],
                16, 0, 0);
        }
    };

    f32x4 acc[NTKV];
#pragma unroll
    for (int nt = 0; nt < NTKV; ++nt) acc[nt] = (f32x4){0.f, 0.f, 0.f, 0.f};

    stage(0, 0);
    __syncthreads();               // drains vmcnt -> Bs[0] ready
#pragma unroll
    for (int ks = 0; ks < KST; ++ks) {
        if (ks + 1 < KST) stage(ks + 1, (ks + 1) & 1);   // DMA flies under MFMAs
        const unsigned short* bs = &Bs[ks & 1][lane * 8];
#pragma unroll
        for (int nt = 0; nt < NTKV; ++nt) {
            const bf16x8 b8 = *(const bf16x8*)(bs + (nt << 9));
            acc[nt] = __builtin_amdgcn_mfma_f32_16x16x32_bf16(a[ks], b8, acc[nt], 0, 0, 0);
        }
        __syncthreads();           // next slab staged + all waves done with cur
    }

#pragma unroll
    for (int nt = 0; nt < NTKV; ++nt) {
        const int col = nt * 16 + lm;               // 0..399
        const float bias = ipb[DM + col];
#pragma unroll
        for (int reg = 0; reg < 4; ++reg) {
            const int grow = M0 + m0 + quad * 4 + reg;
            const float v = acc[nt][reg] + bias;
            if (col < DM) Kp[(size_t)grow * DM + col] = __float2bfloat16(v);
            else          Vp[(size_t)grow * DM + (col - DM)] = __float2bfloat16(v);
        }
    }
}

// ---------------------------------------------------------------------------
// K6: MFMA attention per (b, head). Q read as bf16.
// ---------------------------------------------------------------------------
__global__ __launch_bounds__(256) void k_attn(
    const unsigned short* __restrict__ qb, const __hip_bfloat16* __restrict__ Kp,
    const __hip_bfloat16* __restrict__ Vp, float* __restrict__ obuf)
{
    __shared__ __align__(16) unsigned short Qs[64][72];    // [query][k 0..63]
    __shared__ __align__(16) unsigned short KP[320][72];   // [key][k 0..63]
    __shared__ __align__(16) unsigned short Vt[64][328];   // [e][key]
    __shared__ __align__(16) unsigned short Ps[64][328];   // [query][key]
    const int b = blockIdx.x, hh = blockIdx.y;
    const int t = threadIdx.x;

    const unsigned short* qbase = qb + (size_t)(b * KQN) * DM + hh * HD;
    for (int idx = t; idx < 64 * 64; idx += 256) {
        const int r = idx >> 6, e = idx & 63;
        Qs[r][e] = (e < HD) ? qbase[(size_t)r * DM + e] : 0;
    }
    const unsigned short* kbase = (const unsigned short*)Kp + (size_t)b * TKV * DM + hh * HD;
    for (int idx = t; idx < 320 * 25; idx += 256) {
        const int key = idx / 25, g = idx - key * 25;
        *(unsigned int*)&KP[key][g * 2] =
            *(const unsigned int*)(kbase + (size_t)key * DM + g * 2);
    }
    for (int idx = t; idx < 320 * 7; idx += 256) {   // zero k-pad [50,64)
        const int key = idx / 7, g = idx - key * 7;
        *(unsigned int*)&KP[key][50 + g * 2] = 0;
    }
    const unsigned short* vbase = (const unsigned short*)Vp + (size_t)b * TKV * DM + hh * HD;
    for (int idx = t; idx < 320 * 25; idx += 256) {
        const int key = idx / 25, g = idx - key * 25;
        const unsigned int v = *(const unsigned int*)(vbase + (size_t)key * DM + g * 2);
        Vt[g * 2][key]     = (unsigned short)(v & 0xffffu);
        Vt[g * 2 + 1][key] = (unsigned short)(v >> 16);
    }
    __syncthreads();

    const int w = t >> 6, lane = t & 63;
    const int lm = lane & 15, quad = lane >> 4;
    const int m0 = w * 16;

    f32x4 s[20];
#pragma unroll
    for (int nt = 0; nt < 20; ++nt) s[nt] = (f32x4){0.f, 0.f, 0.f, 0.f};
#pragma unroll
    for (int ks = 0; ks < 2; ++ks) {
        const int ka = ks * 32 + quad * 8;
        const bf16x8 a = *(const bf16x8*)&Qs[m0 + lm][ka];
#pragma unroll
        for (int nt = 0; nt < 20; ++nt) {
            const bf16x8 bb8 = *(const bf16x8*)&KP[nt * 16 + lm][ka];
            s[nt] = __builtin_amdgcn_mfma_f32_16x16x32_bf16(a, bb8, s[nt], 0, 0, 0);
        }
    }

    const float scale = 0.14142135623730951f;  // 1/sqrt(50)
    float inv[4];
#pragma unroll
    for (int reg = 0; reg < 4; ++reg) {
        float mx = -1e30f;
#pragma unroll
        for (int nt = 0; nt < 20; ++nt) {
            const float sv = s[nt][reg] * scale;
            s[nt][reg] = sv;
            mx = fmaxf(mx, sv);
        }
#pragma unroll
        for (int off = 1; off < 16; off <<= 1)
            mx = fmaxf(mx, __shfl_xor(mx, off, 64));
        float lsum = 0.f;
#pragma unroll
        for (int nt = 0; nt < 20; ++nt) {
            const float p = __expf(s[nt][reg] - mx);
            s[nt][reg] = p;
            lsum += p;
        }
#pragma unroll
        for (int off = 1; off < 16; off <<= 1)
            lsum += __shfl_xor(lsum, off, 64);
        inv[reg] = 1.f / lsum;
    }
#pragma unroll
    for (int reg = 0; reg < 4; ++reg) {
        const int row = m0 + quad * 4 + reg;
#pragma unroll
        for (int nt = 0; nt < 20; ++nt)
            Ps[row][nt * 16 + lm] = f2bf(s[nt][reg]);
    }
    __syncthreads();

    f32x4 o[4];
#pragma unroll
    for (int nt = 0; nt < 4; ++nt) o[nt] = (f32x4){0.f, 0.f, 0.f, 0.f};
#pragma unroll
    for (int ks = 0; ks < 10; ++ks) {
        const int ka = ks * 32 + quad * 8;
        const bf16x8 a = *(const bf16x8*)&Ps[m0 + lm][ka];
#pragma unroll
        for (int nt = 0; nt < 4; ++nt) {
            const bf16x8 bb8 = *(const bf16x8*)&Vt[nt * 16 + lm][ka];
            o[nt] = __builtin_amdgcn_mfma_f32_16x16x32_bf16(a, bb8, o[nt], 0, 0, 0);
        }
    }
    float* op = obuf + (size_t)(b * KQN) * DM + hh * HD;
#pragma unroll
    for (int nt = 0; nt < 4; ++nt) {
        const int e = nt * 16 + lm;
        if (e < HD) {
#pragma unroll
            for (int reg = 0; reg < 4; ++reg) {
                const int row = m0 + quad * 4 + reg;
                op[(size_t)row * DM + e] = o[nt][reg] * inv[reg];
            }
        }
    }
}

// ---------------------------------------------------------------------------
// Workspace layout (phase-overlapped, ws = 192,940,032):
//   sel  int [512]               @ 0            (2,048)     [live whole run]
//   -- phase 1 (router):
//   BHp  bf16 packed [4][1000]   @ 4096         (65,536,000)
//   BLp  bf16 packed             @ 65,540,096   (65,536,000)
//   part fp32 [50][512][512]     @ 131,076,096  (52,428,800)
//   h    fp32 [512][512]         @ 183,504,896  ( 1,048,576) -> 184,553,472
//   -- phase 2 (overlaps phase 1 after argmax):
//   q    bf16 [512][64][200]     @ 4096         (13,107,200)
//   Kp   bf16 [512][320][200]    @ 26,776,832   (65,536,000)
//   Vp   bf16 [512][320][200]    @ 92,312,832   (65,536,000)
//   obuf fp32 [512][64][200]     @ 157,848,832  (26,214,400) -> 184,063,232
//   -- weight packs (live whole run; past BOTH phases):
//   Wkv  @ 184,553,472 (179,200)  WqHp @ 184,732,672  WqLp @ 184,825,856
//   OwHp @ 184,919,040  OwLp @ 185,012,224 -> ends 185,105,408 < ws OK
// ---------------------------------------------------------------------------
extern "C" void kernel_launch(void* const* d_in, const int* in_sizes, int n_in,
                              void* d_out, int out_size, void* d_ws, size_t ws_size,
                              hipStream_t stream)
{
    const float* bands = (const float*)d_in[0];
    const float* w1    = (const float*)d_in[1];
    const float* b1    = (const float*)d_in[2];
    const float* w2    = (const float*)d_in[3];
    const float* b2    = (const float*)d_in[4];
    const float* ipw   = (const float*)d_in[5];
    const float* ipb   = (const float*)d_in[6];
    const float* outw  = (const float*)d_in[7];
    const float* outb  = (const float*)d_in[8];
    float* out = (float*)d_out;

    if (ws_size < (size_t)192940032) return;

    char* ws = (char*)d_ws;
    int*   sel  = (int*)  (ws + 0);
    unsigned short* BHp  = (unsigned short*)(ws + 4096);
    unsigned short* BLp  = (unsigned short*)(ws + 65540096);
    float* part = (float*)(ws + 131076096);
    float* h    = (float*)(ws + 183504896);
    unsigned short* qb   = (unsigned short*)(ws + 4096);   // phase 2
    __hip_bfloat16* Kp   = (__hip_bfloat16*)(ws + 26776832);
    __hip_bfloat16* Vp   = (__hip_bfloat16*)(ws + 92312832);
    float* obuf = (float*)(ws + 157848832);
    unsigned short* Wkv  = (unsigned short*)(ws + 184553472);
    unsigned short* WqHp = (unsigned short*)(ws + 184732672);
    unsigned short* WqLp = (unsigned short*)(ws + 184825856);
    unsigned short* OwHp = (unsigned short*)(ws + 184919040);
    unsigned short* OwLp = (unsigned short*)(ws + 185012224);

    // weight preps
    k_wpack_kv<<<KST * NTKV, 256, 0, stream>>>(ipw, Wkv);
    k_wpack<<<dim3(KST * NTT, 2), 256, 0, stream>>>(ipw, outw, WqHp, WqLp, OwHp, OwLp);
    k_splitw1<<<dim3(1000, 4), 256, 0, stream>>>(w1, BHp, BLp);

    k_router_mfma<<<dim3(2, 2, KSPLIT), 512, 0, stream>>>(bands, BHp, BLp, part);
    k_reduce_relu<<<(BATCH * HIDW) / 256, 256, 0, stream>>>(part, b1, h);
    k_argmax<<<BATCH, 256, 0, stream>>>(h, w2, b2, sel);
    // ---- phase 2: phase-1 buffers (BHp/BLp/part/h) are dead from here ----
    k_qproj_mfma<<<BATCH, 256, 0, stream>>>(bands, sel, WqHp, WqLp, ipb, qb);
    k_kvproj_lds<<<2560, 256, 0, stream>>>(bands, Wkv, ipb, Kp, Vp);
    k_attn<<<dim3(BATCH, NHEAD), 256, 0, stream>>>(qb, Kp, Vp, obuf);
    k_outproj_mfma<<<BATCH, 256, 0, stream>>>(obuf, OwHp, OwLp, outb, out);
}

// Round 12
// 800.270 us; speedup vs baseline: 1.0189x; 1.0189x over previous
//
#include <hip/hip_runtime.h>
#include <hip/hip_bf16.h>

// Problem constants
#define NBANDS 5
#define BATCH  512
#define KQN    64     // queries per sample
#define DM     200    // model dim
#define NHEAD  4
#define HD     50     // head dim
#define HIDW   512    // router hidden
#define TKV    320    // NBANDS*KQN keys
#define FIN    64000  // NBANDS*KQN*DM
#define BSTRIDE 6553600  // BATCH*KQN*DM floats per band
#define KSPLIT 50
#define KCH    1280   // FIN/KSPLIT ; 12800/1280=10 -> z-slice within one band
#define NCH    40     // KCH/32 chunks (BK=32) per block
#define NTT    13     // N-tiles of 16 covering 200 (13*16=208)
#define KST    7      // K-steps of 32 covering 200 (7*32=224)
#define NTKV   25     // N-tiles of 16 covering 400

typedef __bf16  bf16x8 __attribute__((ext_vector_type(8)));
typedef float   f32x4  __attribute__((ext_vector_type(4)));

static __device__ inline unsigned short f2bf(float f) {
    __hip_bfloat16 h = __float2bfloat16(f);
    return *reinterpret_cast<unsigned short*>(&h);
}
static __device__ inline float bf2f(unsigned short u) {
    union { unsigned int i; float f; } x;
    x.i = ((unsigned int)u) << 16;
    return x.f;
}
static __device__ inline bf16x8 bf8zero() {
    union { bf16x8 v; unsigned int u[4]; } z;
    z.u[0] = z.u[1] = z.u[2] = z.u[3] = 0u;
    return z.v;
}
// Markidis split of 8 consecutive fp32 into hi/lo bf16x8
static __device__ inline void split8(const float4& a, const float4& b,
                                     bf16x8& hi, bf16x8& lo) {
    union { bf16x8 v; unsigned short u[8]; } H, L;
    const float xs[8] = {a.x, a.y, a.z, a.w, b.x, b.y, b.z, b.w};
#pragma unroll
    for (int i = 0; i < 8; ++i) {
        H.u[i] = f2bf(xs[i]);
        L.u[i] = f2bf(xs[i] - bf2f(H.u[i]));
    }
    hi = H.v; lo = L.v;
}
// plain bf16 round of 8 consecutive fp32
static __device__ inline bf16x8 round8(const float4& a, const float4& b) {
    union { bf16x8 v; unsigned short u[8]; } H;
    const float xs[8] = {a.x, a.y, a.z, a.w, b.x, b.y, b.z, b.w};
#pragma unroll
    for (int i = 0; i < 8; ++i) H.u[i] = f2bf(xs[i]);
    return H.v;
}

// ---------------------------------------------------------------------------
// K0: split w1 into FRAGMENT-MAJOR Markidis hi/lo bf16 planes, once.
// Tile = (oj in [0,4) of 128 rows, kc in [0,1000) of 64 k):
// slot = (ks*8+nt)*64 + lane holds
// w1[oj*128 + nt*16 + (lane&15)][kc*64 + ks*32 + (lane>>4)*8 + e], e=0..7.
// Each ks-half (8 KB/plane, nt 0..7) is CONTIGUOUS -> BK=32 slabs DMA linearly.
// ---------------------------------------------------------------------------
__global__ __launch_bounds__(256) void k_splitw1(
    const float* __restrict__ w1, unsigned short* __restrict__ BHp,
    unsigned short* __restrict__ BLp)
{
    __shared__ __align__(16) unsigned short Hs[128][72];
    __shared__ __align__(16) unsigned short Ls[128][72];
    const int kc = blockIdx.x;        // 0..999
    const int jt = blockIdx.y;        // 0..3
    const int t  = threadIdx.x;
    const int rl0 = t >> 4, cl4 = (t & 15) * 4;
#pragma unroll
    for (int i = 0; i < 8; ++i) {
        const int row = rl0 + i * 16;
        const float4 v = *(const float4*)(w1
            + (size_t)(jt * 128 + row) * FIN + kc * 64 + cl4);
        ushort4 hh, ll;
        hh.x = f2bf(v.x); ll.x = f2bf(v.x - bf2f(hh.x));
        hh.y = f2bf(v.y); ll.y = f2bf(v.y - bf2f(hh.y));
        hh.z = f2bf(v.z); ll.z = f2bf(v.z - bf2f(hh.z));
        hh.w = f2bf(v.w); ll.w = f2bf(v.w - bf2f(hh.w));
        *(ushort4*)&Hs[row][cl4] = hh;
        *(ushort4*)&Ls[row][cl4] = ll;
    }
    __syncthreads();
    const size_t tbase = ((size_t)(jt * 1000 + kc)) << 13;   // ushort units
#pragma unroll
    for (int i = 0; i < 4; ++i) {
        const int slot = i * 256 + t;          // 0..1023
        const int ksnt = slot >> 6, lane = slot & 63;
        const int ks = ksnt >> 3, nt = ksnt & 7;
        const int row = nt * 16 + (lane & 15);
        const int col = ks * 32 + (lane >> 4) * 8;
        *(uint4*)(BHp + tbase + (size_t)slot * 8) = *(const uint4*)&Hs[row][col];
        *(uint4*)(BLp + tbase + (size_t)slot * 8) = *(const uint4*)&Ls[row][col];
    }
}

// ---------------------------------------------------------------------------
// K1 (v7): router GEMM — CO-RESIDENCY fix.
// R10/R11 post-mortem: with 128 KB LDS the 256x256 tile ran 1 block/CU and
// only 200/256 CUs busy; every per-chunk stall (DMA drain, A-load latency,
// barrier reconvergence) was fully exposed (MfmaUtil 25%, nothing saturated;
// FETCH 136 MB shows demand is L3-served, so BW is not the binder). Fix:
// 128x256 tile, grid 2jt x 4bt x 50z = 400 blocks, 512 thr (2wr x 4wc waves,
// per-wave 64x64, acc[4][4]=64 VGPR). LDS: B dbuf 2x32 KB + A single 16 KB
// = 80 KB -> 2 blocks/CU, ALL 400 resident: one block's MFMAs cover the
// other's stalls. B DMA'd one chunk ahead; A prefetch+split to regs one
// chunk ahead. Per-acc product order (AhBh,AlBh,AhBl; k ascending) unchanged
// -> bit-identical logits. Demand 786 MB (A x2, B x4) — L3-served.
// ---------------------------------------------------------------------------
__global__ __launch_bounds__(512, 4) void k_router_mfma(
    const float* __restrict__ bands, const unsigned short* __restrict__ BHp,
    const unsigned short* __restrict__ BLp, float* __restrict__ part)
{
    __shared__ __align__(16) unsigned short BsH[2][8192];   // 2 x 16 KB
    __shared__ __align__(16) unsigned short BsL[2][8192];   // 2 x 16 KB
    __shared__ __align__(16) unsigned short Ah[4096];       // 8 KB
    __shared__ __align__(16) unsigned short Al[4096];       // 8 KB

    // grid: x=jt(2), y=bt(4), z=50 ; 400 blocks = 8 XCD x 50 (bijective)
    const int lin = (blockIdx.z << 3) | (blockIdx.y << 1) | blockIdx.x;
    const int logical = (lin & 7) * 50 + (lin >> 3);
    const int z   = logical >> 3;          // 0..49
    const int rem = logical & 7;
    const int bt  = rem >> 1, jt = rem & 1;

    const int t = threadIdx.x;
    const int w = t >> 6, lane = t & 63;   // w in [0,8)
    const int lm = lane & 15, quad = lane >> 4;
    const int wr = w >> 2, wc = w & 3;     // 2x4 wave grid; wave = 64r x 64c

    // A: this wave stages rows bt*128 + w*16 + lm at k quad*8..+8
    const float* abase = bands + (size_t)(z / 10) * BSTRIDE
                       + (size_t)(bt * 128 + w * 16 + lm) * 12800
                       + (z % 10) * KCH + quad * 8;

    // async stage of one BK=32 B slab (16 KB hi + 16 KB lo) into buffer buf
    auto stageB = [&](int c, int buf) {
        const int kc = z * 20 + (c >> 1);
        const int ks = c & 1;
#pragma unroll
        for (int p = 0; p < 4; ++p) {
            const int plane = p >> 1, oj = p & 1;   // oj: which 128-col half
            const unsigned short* src = (plane ? BLp : BHp)
                + ((size_t)((jt * 2 + oj) * 1000 + kc) << 13) + (ks << 12)
                + (size_t)t * 8;
            unsigned short* dst = (plane ? &BsL[buf][0] : &BsH[buf][0])
                + (oj << 12) + (w << 9);           // + lane*16B by HW
            __builtin_amdgcn_global_load_lds(
                (const __attribute__((address_space(1))) unsigned int*)src,
                (__attribute__((address_space(3))) unsigned int*)dst, 16, 0, 0);
        }
    };

    bf16x8 ahn, aln;  // next chunk's A fragment (this thread's slot)
    auto loadsplitA = [&](int c) {
        const float* ap = abase + c * 32;
        const float4 x0 = *(const float4*)(ap);
        const float4 x1 = *(const float4*)(ap + 4);
        split8(x0, x1, ahn, aln);
    };
    auto writeA = [&]() {
        *(bf16x8*)&Ah[w * 512 + lane * 8] = ahn;
        *(bf16x8*)&Al[w * 512 + lane * 8] = aln;
    };

    f32x4 acc[4][4];
#pragma unroll
    for (int rs = 0; rs < 4; ++rs)
#pragma unroll
        for (int nt = 0; nt < 4; ++nt) acc[rs][nt] = (f32x4){0.f, 0.f, 0.f, 0.f};

    // prologue: A(0) regs -> LDS ; B(0) DMA
    loadsplitA(0);
    stageB(0, 0);
    writeA();
    __syncthreads();                 // drains DMA(0) + publishes A(0)

    const unsigned short* hbase = &BsH[0][((wc >> 1) << 12) + ((wc & 1) * 4) * 512 + lane * 8];
    const unsigned short* lbase = &BsL[0][((wc >> 1) << 12) + ((wc & 1) * 4) * 512 + lane * 8];
    const unsigned short* ahp = &Ah[(wr * 4) * 512 + lane * 8];
    const unsigned short* alp = &Al[(wr * 4) * 512 + lane * 8];

    for (int c = 0; c < NCH; ++c) {
        const int buf = c & 1;
        if (c + 1 < NCH) {           // prefetch next chunk under compute(c)
            stageB(c + 1, buf ^ 1);
            loadsplitA(c + 1);
        }
        // ---- compute chunk c: 48 MFMAs/wave ----
        const unsigned short* hc = hbase + buf * 8192;
        const unsigned short* lc = lbase + buf * 8192;
        bf16x8 af[4], alf[4];
#pragma unroll
        for (int rs = 0; rs < 4; ++rs) {
            af[rs]  = *(const bf16x8*)(ahp + rs * 512);
            alf[rs] = *(const bf16x8*)(alp + rs * 512);
        }
#pragma unroll
        for (int nt = 0; nt < 4; ++nt) {
            const bf16x8 bh = *(const bf16x8*)(hc + nt * 512);
            const bf16x8 bl = *(const bf16x8*)(lc + nt * 512);
#pragma unroll
            for (int rs = 0; rs < 4; ++rs) {
                acc[rs][nt] = __builtin_amdgcn_mfma_f32_16x16x32_bf16(af[rs], bh, acc[rs][nt], 0, 0, 0);
                acc[rs][nt] = __builtin_amdgcn_mfma_f32_16x16x32_bf16(alf[rs], bh, acc[rs][nt], 0, 0, 0);
                acc[rs][nt] = __builtin_amdgcn_mfma_f32_16x16x32_bf16(af[rs], bl, acc[rs][nt], 0, 0, 0);
            }
        }
        __syncthreads();             // A(c) readers done; DMA(c+1) drained
        if (c + 1 < NCH) {
            writeA();                // A(c+1) -> LDS (no readers now)
            __syncthreads();         // publish A(c+1)
        }
    }

    float* po = part + (size_t)z * (BATCH * HIDW);
    const int j0 = jt * 256 + wc * 64;
    const int b0 = bt * 128 + wr * 64;
#pragma unroll
    for (int rs = 0; rs < 4; ++rs) {
#pragma unroll
        for (int nt = 0; nt < 4; ++nt) {
            const int jj = j0 + nt * 16 + lm;
#pragma unroll
            for (int reg = 0; reg < 4; ++reg) {
                const int bb = b0 + rs * 16 + quad * 4 + reg;
                po[(size_t)bb * HIDW + jj] = acc[rs][nt][reg];
            }
        }
    }
}

// ---------------------------------------------------------------------------
// K2: h = relu(sum_z part + b1)
// ---------------------------------------------------------------------------
__global__ __launch_bounds__(256) void k_reduce_relu(
    const float* __restrict__ part, const float* __restrict__ b1,
    float* __restrict__ h)
{
    const int tid = blockIdx.x * 256 + threadIdx.x;  // < BATCH*HIDW
    float s = b1[tid & (HIDW - 1)];
#pragma unroll 10
    for (int z = 0; z < KSPLIT; ++z) s += part[z * (BATCH * HIDW) + tid];
    h[tid] = fmaxf(s, 0.f);
}

// ---------------------------------------------------------------------------
// K2c: pack wq (ipw rows 0..199) and out_w into FRAGMENT-MAJOR Markidis
// hi/lo bf16 planes.
// ---------------------------------------------------------------------------
__global__ __launch_bounds__(256) void k_wpack(
    const float* __restrict__ ipw, const float* __restrict__ outw,
    unsigned short* __restrict__ WqHp, unsigned short* __restrict__ WqLp,
    unsigned short* __restrict__ OwHp, unsigned short* __restrict__ OwLp)
{
    const int p = blockIdx.x;          // 0..90 : ks*13+nt
    const int ks = p / NTT, nt = p - ks * NTT;
    const int t = threadIdx.x;
    const int lane = t >> 2, e0 = (t & 3) * 2;
    const int lm = lane & 15, quad = lane >> 4;
    const int row = nt * 16 + lm;
    const int k  = ks * 32 + quad * 8 + e0;
    const float* src = (blockIdx.y == 0) ? ipw : outw;   // wq = ipw rows 0..199
    unsigned short* dh = (blockIdx.y == 0) ? WqHp : OwHp;
    unsigned short* dl = (blockIdx.y == 0) ? WqLp : OwLp;
    float v0 = 0.f, v1 = 0.f;
    if (row < DM && k < DM) {          // k even, so k<200 => k+1<=199 valid
        v0 = src[(size_t)row * DM + k];
        v1 = src[(size_t)row * DM + k + 1];
    }
    const int off = (p << 9) + (lane << 3) + e0;
    const unsigned short h0 = f2bf(v0), h1 = f2bf(v1);
    dh[off]     = h0;
    dh[off + 1] = h1;
    dl[off]     = f2bf(v0 - bf2f(h0));
    dl[off + 1] = f2bf(v1 - bf2f(h1));
}

// ---------------------------------------------------------------------------
// K2d: pack wk|wv (ipw rows 200..599) into ONE fragment-major bf16 plane.
// ---------------------------------------------------------------------------
__global__ __launch_bounds__(256) void k_wpack_kv(
    const float* __restrict__ ipw, unsigned short* __restrict__ Wkv)
{
    const int p = blockIdx.x;          // 0..174 : ks*25+nt
    const int ks = p / NTKV, nt = p - ks * NTKV;
    const int t = threadIdx.x;
    const int lane = t >> 2, e0 = (t & 3) * 2;
    const int lm = lane & 15, quad = lane >> 4;
    const int row = nt * 16 + lm;                 // 0..399, always valid
    const int k  = ks * 32 + quad * 8 + e0;
    float v0 = 0.f, v1 = 0.f;
    if (k < DM) {
        v0 = ipw[(size_t)(DM + row) * DM + k];
        v1 = ipw[(size_t)(DM + row) * DM + k + 1];
    }
    const int off = (p << 9) + (lane << 3) + e0;
    Wkv[off]     = f2bf(v0);
    Wkv[off + 1] = f2bf(v1);
}

// ---------------------------------------------------------------------------
// K3: logits = h @ w2^T + b2 ; sel = argmax
// ---------------------------------------------------------------------------
__global__ __launch_bounds__(256) void k_argmax(
    const float* __restrict__ h, const float* __restrict__ w2,
    const float* __restrict__ b2, int* __restrict__ sel)
{
    __shared__ float red[NBANDS][256];
    const int b = blockIdx.x, t = threadIdx.x;
    float acc[NBANDS] = {0.f, 0.f, 0.f, 0.f, 0.f};
    for (int j = t; j < HIDW; j += 256) {
        const float hv = h[b * HIDW + j];
#pragma unroll
        for (int n = 0; n < NBANDS; ++n)
            acc[n] = fmaf(hv, w2[n * HIDW + j], acc[n]);
    }
#pragma unroll
    for (int n = 0; n < NBANDS; ++n) red[n][t] = acc[n];
    __syncthreads();
    for (int s = 128; s > 0; s >>= 1) {
        if (t < s) {
#pragma unroll
            for (int n = 0; n < NBANDS; ++n) red[n][t] += red[n][t + s];
        }
        __syncthreads();
    }
    if (t == 0) {
        int best = 0;
        float bv = red[0][0] + b2[0];
        for (int n = 1; n < NBANDS; ++n) {
            const float v = red[n][0] + b2[n];
            if (v > bv) { bv = v; best = n; }
        }
        sel[b] = best;
    }
}

// ---------------------------------------------------------------------------
// Shared MFMA core for the two [64x200]@[200x200]^T projections.
// ---------------------------------------------------------------------------
template<bool BF16OUT>
static __device__ inline void proj_core(
    const float* __restrict__ x0,            // 64 rows x 200 fp32, stride DM
    const unsigned short* __restrict__ Ph,   // packed hi plane
    const unsigned short* __restrict__ Pl,   // packed lo plane
    const float* __restrict__ bias,          // 200
    void* __restrict__ outp)                 // 64 rows x 200 (bf16 or f32)
{
    const int t = threadIdx.x;
    const int w = t >> 6, lane = t & 63;
    const int lm = lane & 15, quad = lane >> 4;
    const int m0 = w * 16;
    const float* xrow = x0 + (size_t)(m0 + lm) * DM;

    f32x4 acc[NTT];
#pragma unroll
    for (int nt = 0; nt < NTT; ++nt) acc[nt] = (f32x4){0.f, 0.f, 0.f, 0.f};

#pragma unroll
    for (int ks = 0; ks < KST; ++ks) {
        const int k0 = ks * 32 + quad * 8;
        bf16x8 a_h = bf8zero(), a_l = bf8zero();
        if (k0 + 8 <= DM) {      // ks=6: only quad 0 (k=192..199) has data
            const float4 xa = *(const float4*)(xrow + k0);
            const float4 xb = *(const float4*)(xrow + k0 + 4);
            split8(xa, xb, a_h, a_l);
        }
        const unsigned short* ph = Ph + ((ks * NTT) << 9) + (lane << 3);
        const unsigned short* pl = Pl + ((ks * NTT) << 9) + (lane << 3);
#pragma unroll
        for (int nt = 0; nt < NTT; ++nt) {
            const bf16x8 b_h = *(const bf16x8*)(ph + (nt << 9));
            const bf16x8 b_l = *(const bf16x8*)(pl + (nt << 9));
            acc[nt] = __builtin_amdgcn_mfma_f32_16x16x32_bf16(a_h, b_h, acc[nt], 0, 0, 0);
            acc[nt] = __builtin_amdgcn_mfma_f32_16x16x32_bf16(a_l, b_h, acc[nt], 0, 0, 0);
            acc[nt] = __builtin_amdgcn_mfma_f32_16x16x32_bf16(a_h, b_l, acc[nt], 0, 0, 0);
        }
    }
#pragma unroll
    for (int nt = 0; nt < NTT; ++nt) {
        const int col = nt * 16 + lm;
        if (col < DM) {
            const float bs = bias[col];
#pragma unroll
            for (int reg = 0; reg < 4; ++reg) {
                const int row = m0 + quad * 4 + reg;
                const float v = acc[nt][reg] + bs;
                if (BF16OUT)
                    ((unsigned short*)outp)[(size_t)row * DM + col] = f2bf(v);
                else
                    ((float*)outp)[(size_t)row * DM + col] = v;
            }
        }
    }
}

// K4: q projection for the selected band -> bf16
__global__ __launch_bounds__(256) void k_qproj_mfma(
    const float* __restrict__ bands, const int* __restrict__ sel,
    const unsigned short* __restrict__ WqHp, const unsigned short* __restrict__ WqLp,
    const float* __restrict__ ipb, unsigned short* __restrict__ qb)
{
    const int b = blockIdx.x;
    const int band = sel[b];
    const float* x0 = bands + (size_t)((band * BATCH + b) * KQN) * DM;
    proj_core<true>(x0, WqHp, WqLp, ipb, qb + (size_t)(b * KQN) * DM);
}

// K7: out = o @ out_w^T + out_b (fp32 out)
__global__ __launch_bounds__(256) void k_outproj_mfma(
    const float* __restrict__ obuf, const unsigned short* __restrict__ OwHp,
    const unsigned short* __restrict__ OwLp, const float* __restrict__ outb,
    float* __restrict__ out)
{
    const int b = blockIdx.x;
    proj_core<false>(obuf + (size_t)(b * KQN) * DM, OwHp, OwLp, outb,
                     out + (size_t)(b * KQN) * DM);
}

// ---------------------------------------------------------------------------
// K5: kv projection — A in registers, B async double-buffered LDS (R4 win).
// ---------------------------------------------------------------------------
__global__ __launch_bounds__(256) void k_kvproj_lds(
    const float* __restrict__ bands, const unsigned short* __restrict__ Wkv,
    const float* __restrict__ ipb, __hip_bfloat16* __restrict__ Kp,
    __hip_bfloat16* __restrict__ Vp)
{
    __shared__ __align__(16) unsigned short Bs[2][NTKV * 512];  // 2 x 25 KB
    const int t = threadIdx.x;
    const int w = t >> 6, lane = t & 63;
    const int lm = lane & 15, quad = lane >> 4;
    const int m0 = w * 16;
    const int M0 = blockIdx.x * 64;

    // this wave's A row: one batch, one band, kk = row within band
    const int gg = M0 + m0 + lm;
    const int bb = gg / TKV, tk = gg - bb * TKV;
    const int band = tk >> 6, kk = tk & 63;
    const float* xrow = bands + (size_t)((band * BATCH + bb) * KQN + kk) * DM;

    float4 ar[2 * KST];
#pragma unroll
    for (int ks = 0; ks < KST; ++ks) {
        const int k0 = ks * 32 + quad * 8;
        if (k0 + 8 <= DM) {
            ar[2 * ks]     = *(const float4*)(xrow + k0);
            ar[2 * ks + 1] = *(const float4*)(xrow + k0 + 4);
        }
    }
    bf16x8 a[KST];
#pragma unroll
    for (int ks = 0; ks < KST; ++ks) {
        const int k0 = ks * 32 + quad * 8;
        a[ks] = (k0 + 8 <= DM) ? round8(ar[2 * ks], ar[2 * ks + 1]) : bf8zero();
    }

    auto stage = [&](int ks, int buf) {
        const unsigned short* src = Wkv + ((ks * NTKV) << 9);
#pragma unroll
        for (int pass = 0; pass < 6; ++pass) {
            const int i = pass * 256 + t;              // 16B-unit index
            __builtin_amdgcn_global_load_lds(
                (const __attribute__((address_space(1))) unsigned int*)(src + (size_t)i * 8),
                (__attribute__((address_space(3))) unsigned int*)&Bs[buf][(pass * 256 + w * 64) * 8],
                16, 0, 0);
        }
        if (t < 64) {                                   // tail: wave 0 only
            __builtin_amdgcn_global_load_lds(
                (const __attribute__((address_space(1))) unsigned int*)(src + (size_t)(1536 + lane) * 8),
                (__attribute__((address_space(3))) unsigned int*)&Bs[buf][1536 * 8],
                16, 0, 0);
        }
    };

    f32x4 acc[NTKV];
#pragma unroll
    for (int nt = 0; nt < NTKV; ++nt) acc[nt] = (f32x4){0.f, 0.f, 0.f, 0.f};

    stage(0, 0);
    __syncthreads();               // drains vmcnt -> Bs[0] ready
#pragma unroll
    for (int ks = 0; ks < KST; ++ks) {
        if (ks + 1 < KST) stage(ks + 1, (ks + 1) & 1);   // DMA flies under MFMAs
        const unsigned short* bs = &Bs[ks & 1][lane * 8];
#pragma unroll
        for (int nt = 0; nt < NTKV; ++nt) {
            const bf16x8 b8 = *(const bf16x8*)(bs + (nt << 9));
            acc[nt] = __builtin_amdgcn_mfma_f32_16x16x32_bf16(a[ks], b8, acc[nt], 0, 0, 0);
        }
        __syncthreads();           // next slab staged + all waves done with cur
    }

#pragma unroll
    for (int nt = 0; nt < NTKV; ++nt) {
        const int col = nt * 16 + lm;               // 0..399
        const float bias = ipb[DM + col];
#pragma unroll
        for (int reg = 0; reg < 4; ++reg) {
            const int grow = M0 + m0 + quad * 4 + reg;
            const float v = acc[nt][reg] + bias;
            if (col < DM) Kp[(size_t)grow * DM + col] = __float2bfloat16(v);
            else          Vp[(size_t)grow * DM + (col - DM)] = __float2bfloat16(v);
        }
    }
}

// ---------------------------------------------------------------------------
// K6: MFMA attention per (b, head). Q read as bf16.
// ---------------------------------------------------------------------------
__global__ __launch_bounds__(256) void k_attn(
    const unsigned short* __restrict__ qb, const __hip_bfloat16* __restrict__ Kp,
    const __hip_bfloat16* __restrict__ Vp, float* __restrict__ obuf)
{
    __shared__ __align__(16) unsigned short Qs[64][72];    // [query][k 0..63]
    __shared__ __align__(16) unsigned short KP[320][72];   // [key][k 0..63]
    __shared__ __align__(16) unsigned short Vt[64][328];   // [e][key]
    __shared__ __align__(16) unsigned short Ps[64][328];   // [query][key]
    const int b = blockIdx.x, hh = blockIdx.y;
    const int t = threadIdx.x;

    const unsigned short* qbase = qb + (size_t)(b * KQN) * DM + hh * HD;
    for (int idx = t; idx < 64 * 64; idx += 256) {
        const int r = idx >> 6, e = idx & 63;
        Qs[r][e] = (e < HD) ? qbase[(size_t)r * DM + e] : 0;
    }
    const unsigned short* kbase = (const unsigned short*)Kp + (size_t)b * TKV * DM + hh * HD;
    for (int idx = t; idx < 320 * 25; idx += 256) {
        const int key = idx / 25, g = idx - key * 25;
        *(unsigned int*)&KP[key][g * 2] =
            *(const unsigned int*)(kbase + (size_t)key * DM + g * 2);
    }
    for (int idx = t; idx < 320 * 7; idx += 256) {   // zero k-pad [50,64)
        const int key = idx / 7, g = idx - key * 7;
        *(unsigned int*)&KP[key][50 + g * 2] = 0;
    }
    const unsigned short* vbase = (const unsigned short*)Vp + (size_t)b * TKV * DM + hh * HD;
    for (int idx = t; idx < 320 * 25; idx += 256) {
        const int key = idx / 25, g = idx - key * 25;
        const unsigned int v = *(const unsigned int*)(vbase + (size_t)key * DM + g * 2);
        Vt[g * 2][key]     = (unsigned short)(v & 0xffffu);
        Vt[g * 2 + 1][key] = (unsigned short)(v >> 16);
    }
    __syncthreads();

    const int w = t >> 6, lane = t & 63;
    const int lm = lane & 15, quad = lane >> 4;
    const int m0 = w * 16;

    f32x4 s[20];
#pragma unroll
    for (int nt = 0; nt < 20; ++nt) s[nt] = (f32x4){0.f, 0.f, 0.f, 0.f};
#pragma unroll
    for (int ks = 0; ks < 2; ++ks) {
        const int ka = ks * 32 + quad * 8;
        const bf16x8 a = *(const bf16x8*)&Qs[m0 + lm][ka];
#pragma unroll
        for (int nt = 0; nt < 20; ++nt) {
            const bf16x8 bb8 = *(const bf16x8*)&KP[nt * 16 + lm][ka];
            s[nt] = __builtin_amdgcn_mfma_f32_16x16x32_bf16(a, bb8, s[nt], 0, 0, 0);
        }
    }

    const float scale = 0.14142135623730951f;  // 1/sqrt(50)
    float inv[4];
#pragma unroll
    for (int reg = 0; reg < 4; ++reg) {
        float mx = -1e30f;
#pragma unroll
        for (int nt = 0; nt < 20; ++nt) {
            const float sv = s[nt][reg] * scale;
            s[nt][reg] = sv;
            mx = fmaxf(mx, sv);
        }
#pragma unroll
        for (int off = 1; off < 16; off <<= 1)
            mx = fmaxf(mx, __shfl_xor(mx, off, 64));
        float lsum = 0.f;
#pragma unroll
        for (int nt = 0; nt < 20; ++nt) {
            const float p = __expf(s[nt][reg] - mx);
            s[nt][reg] = p;
            lsum += p;
        }
#pragma unroll
        for (int off = 1; off < 16; off <<= 1)
            lsum += __shfl_xor(lsum, off, 64);
        inv[reg] = 1.f / lsum;
    }
#pragma unroll
    for (int reg = 0; reg < 4; ++reg) {
        const int row = m0 + quad * 4 + reg;
#pragma unroll
        for (int nt = 0; nt < 20; ++nt)
            Ps[row][nt * 16 + lm] = f2bf(s[nt][reg]);
    }
    __syncthreads();

    f32x4 o[4];
#pragma unroll
    for (int nt = 0; nt < 4; ++nt) o[nt] = (f32x4){0.f, 0.f, 0.f, 0.f};
#pragma unroll
    for (int ks = 0; ks < 10; ++ks) {
        const int ka = ks * 32 + quad * 8;
        const bf16x8 a = *(const bf16x8*)&Ps[m0 + lm][ka];
#pragma unroll
        for (int nt = 0; nt < 4; ++nt) {
            const bf16x8 bb8 = *(const bf16x8*)&Vt[nt * 16 + lm][ka];
            o[nt] = __builtin_amdgcn_mfma_f32_16x16x32_bf16(a, bb8, o[nt], 0, 0, 0);
        }
    }
    float* op = obuf + (size_t)(b * KQN) * DM + hh * HD;
#pragma unroll
    for (int nt = 0; nt < 4; ++nt) {
        const int e = nt * 16 + lm;
        if (e < HD) {
#pragma unroll
            for (int reg = 0; reg < 4; ++reg) {
                const int row = m0 + quad * 4 + reg;
                op[(size_t)row * DM + e] = o[nt][reg] * inv[reg];
            }
        }
    }
}

// ---------------------------------------------------------------------------
// Workspace layout (phase-overlapped, ws = 192,940,032):
//   sel  int [512]               @ 0            (2,048)     [live whole run]
//   -- phase 1 (router):
//   BHp  bf16 packed [4][1000]   @ 4096         (65,536,000)
//   BLp  bf16 packed             @ 65,540,096   (65,536,000)
//   part fp32 [50][512][512]     @ 131,076,096  (52,428,800)
//   h    fp32 [512][512]         @ 183,504,896  ( 1,048,576) -> 184,553,472
//   -- phase 2 (overlaps phase 1 after argmax):
//   q    bf16 [512][64][200]     @ 4096         (13,107,200)
//   Kp   bf16 [512][320][200]    @ 26,776,832   (65,536,000)
//   Vp   bf16 [512][320][200]    @ 92,312,832   (65,536,000)
//   obuf fp32 [512][64][200]     @ 157,848,832  (26,214,400) -> 184,063,232
//   -- weight packs (live whole run; past BOTH phases):
//   Wkv  @ 184,553,472 (179,200)  WqHp @ 184,732,672  WqLp @ 184,825,856
//   OwHp @ 184,919,040  OwLp @ 185,012,224 -> ends 185,105,408 < ws OK
// ---------------------------------------------------------------------------
extern "C" void kernel_launch(void* const* d_in, const int* in_sizes, int n_in,
                              void* d_out, int out_size, void* d_ws, size_t ws_size,
                              hipStream_t stream)
{
    const float* bands = (const float*)d_in[0];
    const float* w1    = (const float*)d_in[1];
    const float* b1    = (const float*)d_in[2];
    const float* w2    = (const float*)d_in[3];
    const float* b2    = (const float*)d_in[4];
    const float* ipw   = (const float*)d_in[5];
    const float* ipb   = (const float*)d_in[6];
    const float* outw  = (const float*)d_in[7];
    const float* outb  = (const float*)d_in[8];
    float* out = (float*)d_out;

    if (ws_size < (size_t)192940032) return;

    char* ws = (char*)d_ws;
    int*   sel  = (int*)  (ws + 0);
    unsigned short* BHp  = (unsigned short*)(ws + 4096);
    unsigned short* BLp  = (unsigned short*)(ws + 65540096);
    float* part = (float*)(ws + 131076096);
    float* h    = (float*)(ws + 183504896);
    unsigned short* qb   = (unsigned short*)(ws + 4096);   // phase 2
    __hip_bfloat16* Kp   = (__hip_bfloat16*)(ws + 26776832);
    __hip_bfloat16* Vp   = (__hip_bfloat16*)(ws + 92312832);
    float* obuf = (float*)(ws + 157848832);
    unsigned short* Wkv  = (unsigned short*)(ws + 184553472);
    unsigned short* WqHp = (unsigned short*)(ws + 184732672);
    unsigned short* WqLp = (unsigned short*)(ws + 184825856);
    unsigned short* OwHp = (unsigned short*)(ws + 184919040);
    unsigned short* OwLp = (unsigned short*)(ws + 185012224);

    // weight preps
    k_wpack_kv<<<KST * NTKV, 256, 0, stream>>>(ipw, Wkv);
    k_wpack<<<dim3(KST * NTT, 2), 256, 0, stream>>>(ipw, outw, WqHp, WqLp, OwHp, OwLp);
    k_splitw1<<<dim3(1000, 4), 256, 0, stream>>>(w1, BHp, BLp);

    k_router_mfma<<<dim3(2, 4, KSPLIT), 512, 0, stream>>>(bands, BHp, BLp, part);
    k_reduce_relu<<<(BATCH * HIDW) / 256, 256, 0, stream>>>(part, b1, h);
    k_argmax<<<BATCH, 256, 0, stream>>>(h, w2, b2, sel);
    // ---- phase 2: phase-1 buffers (BHp/BLp/part/h) are dead from here ----
    k_qproj_mfma<<<BATCH, 256, 0, stream>>>(bands, sel, WqHp, WqLp, ipb, qb);
    k_kvproj_lds<<<2560, 256, 0, stream>>>(bands, Wkv, ipb, Kp, Vp);
    k_attn<<<dim3(BATCH, NHEAD), 256, 0, stream>>>(qb, Kp, Vp, obuf);
    k_outproj_mfma<<<BATCH, 256, 0, stream>>>(obuf, OwHp, OwLp, outb, out);
}